// Round 5
// baseline (735.764 us; speedup 1.0000x reference)
//
#include <hip/hip_runtime.h>
#include <hip/hip_bf16.h>

// Problem constants
#define KN 2048
#define BB 4
#define DM 512
#define NH 8
#define HE 64
#define UP 40
#define NBH 32          // B*H
#define NROWS 8192      // KN*B
#define MiB(x) ((size_t)(x) << 20)

// ---------------------------------------------------------------------------
// Tiled f32 GEMM:  C[m,o] = (sum_k A[m,k]*W[o,k] + bias[o]) * scale
// A: M x 512 row-major (M=8192), W: 512 x 512 row-major, C: M x 512 row-major
// tile 64x64, K-step 32, 256 threads, 4x4 register blocking per thread
// ---------------------------------------------------------------------------
__global__ __launch_bounds__(256) void gemm_bt(
    const float* __restrict__ A, const float* __restrict__ W,
    const float* __restrict__ bias, float scale, float* __restrict__ C) {
  __shared__ float As[32][68];   // [k][m], padded
  __shared__ float Ws[32][68];   // [k][o]
  const int m0 = blockIdx.y * 64;
  const int o0 = blockIdx.x * 64;
  const int tid = threadIdx.x;
  const int tx = tid & 15;
  const int ty = tid >> 4;
  float acc[4][4] = {};

  for (int k0 = 0; k0 < 512; k0 += 32) {
#pragma unroll
    for (int i = 0; i < 2; ++i) {
      int flat = tid + i * 256;      // 0..511
      int r = flat >> 3;             // 0..63
      int c4 = flat & 7;             // 0..7
      float4 av = *(const float4*)(A + (size_t)(m0 + r) * 512 + k0 + c4 * 4);
      float4 wv = *(const float4*)(W + (size_t)(o0 + r) * 512 + k0 + c4 * 4);
      As[c4 * 4 + 0][r] = av.x; As[c4 * 4 + 1][r] = av.y;
      As[c4 * 4 + 2][r] = av.z; As[c4 * 4 + 3][r] = av.w;
      Ws[c4 * 4 + 0][r] = wv.x; Ws[c4 * 4 + 1][r] = wv.y;
      Ws[c4 * 4 + 2][r] = wv.z; Ws[c4 * 4 + 3][r] = wv.w;
    }
    __syncthreads();
#pragma unroll
    for (int kk = 0; kk < 32; ++kk) {
      float a_[4], w_[4];
#pragma unroll
      for (int i = 0; i < 4; ++i) a_[i] = As[kk][ty * 4 + i];
#pragma unroll
      for (int j = 0; j < 4; ++j) w_[j] = Ws[kk][tx * 4 + j];
#pragma unroll
      for (int i = 0; i < 4; ++i)
#pragma unroll
        for (int j = 0; j < 4; ++j)
          acc[i][j] = fmaf(a_[i], w_[j], acc[i][j]);
    }
    __syncthreads();
  }

#pragma unroll
  for (int i = 0; i < 4; ++i) {
    int m = m0 + ty * 4 + i;
#pragma unroll
    for (int j = 0; j < 4; ++j) {
      int o = o0 + tx * 4 + j;
      C[(size_t)m * 512 + o] = (acc[i][j] + bias[o]) * scale;
    }
  }
}

// ---------------------------------------------------------------------------
// M scores: one thread per (bh, n).
// M[bh,n] = max_s dot(Q[n],K[idx[n,s]]) - (sum_s dot)/KN,  s in [0,40)
// Q,K layout: row (n,b,h) contiguous 64 floats at ((n*4+b)*8+h)*64
// ---------------------------------------------------------------------------
__global__ __launch_bounds__(256) void mscore_kernel(
    const float* __restrict__ Q, const float* __restrict__ K,
    const int* __restrict__ idx, float* __restrict__ Mout) {
  const int t = blockIdx.x * 256 + threadIdx.x;   // [0, 65536)
  const int bh = t >> 11;
  const int n = t & 2047;
  const int b = bh >> 3, h = bh & 7;

  float q[64];
  const float4* qrow = (const float4*)(Q + (((size_t)n * 4 + b) * 8 + h) * 64);
#pragma unroll
  for (int e4 = 0; e4 < 16; ++e4) {
    float4 v = qrow[e4];
    q[4 * e4 + 0] = v.x; q[4 * e4 + 1] = v.y;
    q[4 * e4 + 2] = v.z; q[4 * e4 + 3] = v.w;
  }

  float mx = -INFINITY, sm = 0.f;
  for (int s = 0; s < UP; ++s) {
    const int kn = idx[n * UP + s];
    const float4* kr = (const float4*)(K + (((size_t)kn * 4 + b) * 8 + h) * 64);
    float d = 0.f;
#pragma unroll
    for (int e4 = 0; e4 < 16; ++e4) {
      float4 kv = kr[e4];
      d += q[4 * e4 + 0] * kv.x + q[4 * e4 + 1] * kv.y +
           q[4 * e4 + 2] * kv.z + q[4 * e4 + 3] * kv.w;
    }
    mx = fmaxf(mx, d);
    sm += d;
  }
  Mout[t] = mx - sm * (1.0f / (float)KN);
}

// ---------------------------------------------------------------------------
// top-40 per (b,h): iterative argmax, lowest-index tiebreak
// ---------------------------------------------------------------------------
__global__ __launch_bounds__(256) void topk_kernel(
    const float* __restrict__ M, int* __restrict__ Mtop) {
  const int bh = blockIdx.x;
  __shared__ float vals[2048];
  __shared__ float rv[256];
  __shared__ int ri[256];
  const float* Mrow = M + (size_t)bh * 2048;
  for (int i = threadIdx.x; i < 2048; i += 256) vals[i] = Mrow[i];
  __syncthreads();
  for (int it = 0; it < UP; ++it) {
    float bv = -INFINITY; int bi = 0x7fffffff;
    for (int i = threadIdx.x; i < 2048; i += 256) {
      float v = vals[i];
      if (v > bv) { bv = v; bi = i; }
    }
    rv[threadIdx.x] = bv; ri[threadIdx.x] = bi;
    __syncthreads();
    for (int st = 128; st; st >>= 1) {
      if (threadIdx.x < st) {
        float ov = rv[threadIdx.x + st]; int oi = ri[threadIdx.x + st];
        float cv = rv[threadIdx.x];      int ci = ri[threadIdx.x];
        if (ov > cv || (ov == cv && oi < ci)) { rv[threadIdx.x] = ov; ri[threadIdx.x] = oi; }
      }
      __syncthreads();
    }
    if (threadIdx.x == 0) { Mtop[bh * UP + it] = ri[0]; vals[ri[0]] = -INFINITY; }
    __syncthreads();
  }
}

// ---------------------------------------------------------------------------
// mean of V over n per (b,h,e)
// ---------------------------------------------------------------------------
__global__ __launch_bounds__(256) void meanv_kernel(
    const float* __restrict__ V, float* __restrict__ meanV) {
  const int bh = blockIdx.x;
  const int b = bh >> 3, h = bh & 7;
  const int wv = threadIdx.x >> 6, lane = threadIdx.x & 63;
  __shared__ float part[4][64];
  float acc = 0.f;
  for (int n = wv; n < 2048; n += 4)
    acc += V[(((size_t)n * 4 + b) * 8 + h) * 64 + lane];
  part[wv][lane] = acc;
  __syncthreads();
  if (threadIdx.x < 64) {
    float s = part[0][threadIdx.x] + part[1][threadIdx.x] +
              part[2][threadIdx.x] + part[3][threadIdx.x];
    meanV[bh * 64 + threadIdx.x] = s * (1.0f / (float)KN);
  }
}

// ---------------------------------------------------------------------------
// Attention for selected queries: one block per (bh, s).
// ---------------------------------------------------------------------------
__global__ __launch_bounds__(256) void attn_kernel(
    const float* __restrict__ Q, const float* __restrict__ K,
    const float* __restrict__ V, const int* __restrict__ Mtop,
    float* __restrict__ upd) {
  const int blk = blockIdx.x;          // bh*40 + s
  const int bh = blk / UP;
  const int b = bh >> 3, h = bh & 7;
  const int tid = threadIdx.x;

  __shared__ float qs[64];
  __shared__ float p[2048];
  __shared__ float red[256];

  const int nq = Mtop[blk];
  if (tid < 64) qs[tid] = Q[(((size_t)nq * 4 + b) * 8 + h) * 64 + tid];
  __syncthreads();

  float myscore[8];
  float pmax = -INFINITY;
#pragma unroll
  for (int j = 0; j < 8; ++j) {
    int n = tid + j * 256;
    const float* krow = K + (((size_t)n * 4 + b) * 8 + h) * 64;
    float dot = 0.f;
#pragma unroll
    for (int e = 0; e < 64; e += 4) {
      float4 kv = *(const float4*)(krow + e);
      dot += qs[e + 0] * kv.x + qs[e + 1] * kv.y + qs[e + 2] * kv.z + qs[e + 3] * kv.w;
    }
    myscore[j] = dot;
    pmax = fmaxf(pmax, dot);
  }
  red[tid] = pmax; __syncthreads();
  for (int st = 128; st; st >>= 1) {
    if (tid < st) red[tid] = fmaxf(red[tid], red[tid + st]);
    __syncthreads();
  }
  const float m = red[0];
  __syncthreads();
  float psum = 0.f;
#pragma unroll
  for (int j = 0; j < 8; ++j) {
    float e_ = __expf(myscore[j] - m);
    p[tid + j * 256] = e_;
    psum += e_;
  }
  red[tid] = psum; __syncthreads();
  for (int st = 128; st; st >>= 1) {
    if (tid < st) red[tid] += red[tid + st];
    __syncthreads();
  }
  const float denom = red[0];

  const int wv = tid >> 6, lane = tid & 63;
  float acc = 0.f;
#pragma unroll 4
  for (int n = wv * 512; n < wv * 512 + 512; ++n) {
    acc += p[n] * V[(((size_t)n * 4 + b) * 8 + h) * 64 + lane];
  }
  __syncthreads();
  p[wv * 64 + lane] = acc;
  __syncthreads();
  if (tid < 64) {
    float r = (p[tid] + p[64 + tid] + p[128 + tid] + p[192 + tid]) / denom;
    upd[(size_t)blk * 64 + tid] = r;
  }
}

// ---------------------------------------------------------------------------
// ctx fill: ctx[(b*2048+n)*512 + d] = meanV[(b*8+h)*64+e],  d = h*64+e
// ---------------------------------------------------------------------------
__global__ void fillctx_kernel(const float* __restrict__ meanV,
                               float* __restrict__ ctx) {
  size_t i = ((size_t)blockIdx.x * 256 + threadIdx.x) * 4;  // element index
  int d = (int)(i & 511);
  int b = (int)(i >> 20);   // / (2048*512)
  float4 v = *(const float4*)(meanV + (b << 9) + d);
  *(float4*)(ctx + i) = v;
}

// ---------------------------------------------------------------------------
// scatter selected rows: ctx[(b*2048+n)*512 + h*64 + e] = upd[blk*64 + e]
// ---------------------------------------------------------------------------
__global__ void scatter_kernel(const float* __restrict__ upd,
                               const int* __restrict__ Mtop,
                               float* __restrict__ ctx) {
  const int blk = blockIdx.x;   // bh*40 + s
  const int bh = blk / UP;
  const int b = bh >> 3, h = bh & 7;
  const int n = Mtop[blk];
  ctx[((size_t)(b * 2048 + n)) * 512 + h * 64 + threadIdx.x] =
      upd[(size_t)blk * 64 + threadIdx.x];
}

// ---------------------------------------------------------------------------
// Workspace layout (49 MiB; ctx ALIASES Q — Q dead after attn_kernel):
//   [0,       256K)   Mbuf   32*2048 f32
//   [256K,    576K)   upd    1280*64 f32
//   [589824,  598016) mnV    32*64 f32
//   [598016,  603136) Mtop   1280 i32
//   [1M, 17M) Q (ctx alias)   [17M, 33M) K   [33M, 49M) V
// ---------------------------------------------------------------------------
extern "C" void kernel_launch(void* const* d_in, const int* in_sizes, int n_in,
                              void* d_out, int out_size, void* d_ws,
                              size_t ws_size, hipStream_t stream) {
  const float* query = (const float*)d_in[0];
  const float* key   = (const float*)d_in[1];
  const float* value = (const float*)d_in[2];
  const int*   idxs  = (const int*)d_in[3];
  const float* Wq = (const float*)d_in[4];
  const float* bq = (const float*)d_in[5];
  const float* Wk = (const float*)d_in[6];
  const float* bk = (const float*)d_in[7];
  const float* Wv = (const float*)d_in[8];
  const float* bv = (const float*)d_in[9];
  const float* Wo = (const float*)d_in[10];
  const float* bo = (const float*)d_in[11];
  float* out = (float*)d_out;    // reference output dtype is float32

  char* ws = (char*)d_ws;
  float* Mbuf = (float*)(ws + 0);
  float* upd  = (float*)(ws + 262144);
  float* mnV  = (float*)(ws + 589824);
  int*   Mtop = (int*)  (ws + 598016);
  float* Q    = (float*)(ws + MiB(1));
  float* K    = (float*)(ws + MiB(17));
  float* V    = (float*)(ws + MiB(33));
  float* ctx  = Q;   // Q dead after attn_kernel; ctx written afterwards

  dim3 g(8, 128), blk(256);
  gemm_bt<<<g, blk, 0, stream>>>(query, Wq, bq, 0.125f, Q);
  gemm_bt<<<g, blk, 0, stream>>>(key,   Wk, bk, 1.0f,   K);
  gemm_bt<<<g, blk, 0, stream>>>(value, Wv, bv, 1.0f,   V);

  mscore_kernel<<<256, 256, 0, stream>>>(Q, K, idxs, Mbuf);
  topk_kernel<<<NBH, 256, 0, stream>>>(Mbuf, Mtop);
  meanv_kernel<<<NBH, 256, 0, stream>>>(V, mnV);
  attn_kernel<<<NBH * UP, 256, 0, stream>>>(Q, K, V, Mtop, upd);

  fillctx_kernel<<<4096, 256, 0, stream>>>(mnV, ctx);
  scatter_kernel<<<NBH * UP, 64, 0, stream>>>(upd, Mtop, ctx);

  gemm_bt<<<g, blk, 0, stream>>>(ctx, Wo, bo, 1.0f, out);
}